// Round 5
// baseline (411.397 us; speedup 1.0000x reference)
//
#include <hip/hip_runtime.h>
#include <hip/hip_bf16.h>

// ---- problem constants ----
#define OUT_CH   31
#define COEF_LEN 7688                 // 31*31*8
#define NPIX     16384                // 128*128
#define CHUNKS   31                   // KAN input channels (independent param groups)
#define NFRG     24                   // param fragments per chunk (384 padded rows)
#define NR       9                    // K-steps: r = ky*3+kx; k-in-step = conv channel ci
#define FRAG_U16 512                  // u16 per fragment (64 lanes x 8)
#define BP3_B    ((size_t)CHUNKS*NR*NFRG*FRAG_U16*2)   // 6,856,704
#define BIAS_ELE (CHUNKS*NFRG*16)     // 11904 f32
#define NCG      8                    // chunk groups (one per XCD)
#define PART_ELE ((size_t)NCG*OUT_CH*NPIX)             // 4,063,232 f32
#define WS_NEED  (BP3_B + (size_t)BIAS_ELE*4 + PART_ELE*4)

#define SLAB_STRIDE 40                // u16 slots per (row,col): 80B, 16B-aligned
#define LDS_BYTES   (3*130*SLAB_STRIDE*2)              // 31200

using f32x4 = __attribute__((ext_vector_type(4))) float;
using s16x8 = __attribute__((ext_vector_type(8))) short;

__device__ __forceinline__ unsigned short f2bf(float f) {
    unsigned int u = __float_as_uint(f);
    unsigned int r = (u + 0x7FFFu + ((u >> 16) & 1u)) >> 16;
    return (unsigned short)r;
}

// ---------------------------------------------------------------------------
// Pack gen_w/gen_b into bf16 A-fragment layout + bias table.
//  bp3[i][r][f][lane][8] bf16  (frags for one (i,r) contiguous).
//   M-row m = lane&15; k-in-step = (lane>>4)*8 + jj = conv input channel ci.
//   param identity: o = (m>>2)*8 + f/3, jslot = (f%3)*4 + (m&3)
//     jslot 0..7 = coef j, 8 = univ, 9 = res, 10..11 = zero pad
//   value = gw[p][ci][r]; zero for ci==31 / o==31 / pad slots.
//  bias_pk[i][f][m] f32 = gb[p].
// ---------------------------------------------------------------------------
__global__ void pack_kernel(const float* __restrict__ gw, const float* __restrict__ gb,
                            unsigned short* __restrict__ bp, float* __restrict__ bias_pk) {
    const long NU = (long)CHUNKS * NR * NFRG * 64;
    long tt = (long)blockIdx.x * 256 + threadIdx.x;
    if (tt < NU) {
        int lane = (int)(tt & 63);
        long u = tt >> 6;
        int f = (int)(u % NFRG);
        long v = u / NFRG;
        int r = (int)(v % NR);
        int i = (int)(v / NR);
        int m = lane & 15, q8 = lane >> 4;
        int o = (m >> 2) * 8 + f / 3;
        int jslot = (f % 3) * 4 + (m & 3);
        s16x8 w;
        #pragma unroll
        for (int jj = 0; jj < 8; ++jj) {
            int ci = q8 * 8 + jj;
            float val = 0.f;
            if (ci < 31 && o < OUT_CH && jslot < 10) {
                int p;
                if (jslot < 8)       p = i * 248 + o * 8 + jslot;
                else if (jslot == 8) p = COEF_LEN + i * 31 + o;
                else                 p = COEF_LEN + 961 + i * 31 + o;
                val = gw[(long)p * 279 + ci * 9 + r];
            }
            w[jj] = (short)f2bf(val);
        }
        *reinterpret_cast<s16x8*>(bp + tt * 8) = w;
    } else if (tt < NU + BIAS_ELE) {
        long u = tt - NU;
        int m = (int)(u & 15);
        long t2 = u >> 4;
        int f = (int)(t2 % NFRG);
        int i = (int)(t2 / NFRG);
        int o = (m >> 2) * 8 + f / 3;
        int jslot = (f % 3) * 4 + (m & 3);
        float val = 0.f;
        if (o < OUT_CH && jslot < 10) {
            int p;
            if (jslot < 8)       p = i * 248 + o * 8 + jslot;
            else if (jslot == 8) p = COEF_LEN + i * 31 + o;
            else                 p = COEF_LEN + 961 + i * 31 + o;
            val = gb[p];
        }
        bias_pk[u] = val;
    }
}

// ---------------------------------------------------------------------------
// Fused conv-GEMM + KAN epilogue; register-budget-first, barrier-free.
// Grid 1024 = 128 image rows x 8 chunk-groups (cg = bid&7 -> one cg per XCD,
// params L2-resident). Block = 512 thr = 8 waves; wave wm owns frags
// [3*wm, 3*wm+3) (zero A duplication); all waves cover the row's 128 px
// (8 pixel-groups of 16). acc[3][8]=96 VGPR; total ~200 < 256-reg cap
// (launch_bounds(512,2)) -> NO scratch spills. A-frags read global->VGPR
// (reg double-buffer, 1-step lookahead); B from bf16 LDS slab; one
// __syncthreads total. Output: one o per lane (o = q*8+wm), reg-accumulated,
// written to per-cg partials (reduce kernel) or atomicAdd fallback.
// ---------------------------------------------------------------------------
__global__ void __launch_bounds__(512, 2)
main_kernel(const float* __restrict__ x, const unsigned short* __restrict__ bp3,
            const float* __restrict__ bias_pk, float* __restrict__ dst, int use_part) {
    extern __shared__ char smem[];
    unsigned short* slab = (unsigned short*)smem;   // [3][130][40] u16
    const int tid = threadIdx.x;
    const int bid = blockIdx.x;
    const int cg = bid & 7;
    const int pb = bid >> 3;                        // image row
    const int c0 = cg * 4;
    const int c1 = (c0 + 4 < CHUNKS) ? c0 + 4 : CHUNKS;

    // slab: rows pb-1..pb+1, cols -1..128, all 31 channels (bf16), zero-padded
    for (int idx = tid; idx < 3 * 130 * 32; idx += 512) {
        int slot = idx & 31;
        int t = idx >> 5;
        int cc = t % 130;
        int rr = t / 130;
        int hh = pb - 1 + rr, ww = cc - 1;
        float v = 0.f;
        if (slot < 31 && (unsigned)hh < 128u && (unsigned)ww < 128u)
            v = x[slot * NPIX + hh * 128 + ww];
        slab[(rr * 130 + cc) * SLAB_STRIDE + slot] = f2bf(v);
    }
    __syncthreads();
    // ---- no further barriers ----

    const int lane = tid & 63;
    const int wm = tid >> 6;        // 0..7: frags [3*wm, 3*wm+3)
    const int q = lane >> 4;
    const int pix16 = lane & 15;
    const int lane8 = lane * 8;

    int sa[8];
    #pragma unroll
    for (int pg = 0; pg < 8; ++pg)
        sa[pg] = (pg * 16 + pix16) * (SLAB_STRIDE * 2) + q * 16;   // byte offset

    float oreg[8];
    #pragma unroll
    for (int pg = 0; pg < 8; ++pg) oreg[pg] = 0.f;

    #pragma unroll 1
    for (int ic = c0; ic < c1; ++ic) {
        // acc init = bias
        f32x4 acc[3][8];
        const float* bb = bias_pk + ((size_t)ic * NFRG + wm * 3) * 16 + q * 4;
        #pragma unroll
        for (int fl = 0; fl < 3; ++fl) {
            f32x4 b = *reinterpret_cast<const f32x4*>(bb + fl * 16);
            #pragma unroll
            for (int pg = 0; pg < 8; ++pg) acc[fl][pg] = b;
        }

        const unsigned short* abase = bp3 + (size_t)(ic * NR * NFRG + wm * 3) * FRAG_U16 + lane8;
        s16x8 pa[2][3];
        #pragma unroll
        for (int fl = 0; fl < 3; ++fl)
            pa[0][fl] = *reinterpret_cast<const s16x8*>(abase + fl * FRAG_U16);

        #pragma unroll
        for (int r = 0; r < NR; ++r) {
            if (r + 1 < NR) {      // prefetch next K-step's A frags (reg dbuf)
                #pragma unroll
                for (int fl = 0; fl < 3; ++fl)
                    pa[(r + 1) & 1][fl] = *reinterpret_cast<const s16x8*>(
                        abase + ((r + 1) * NFRG + fl) * FRAG_U16);
            }
            const int roff = ((r / 3) * 130 + (r % 3)) * (SLAB_STRIDE * 2);
            s16x8 pbv[8];
            #pragma unroll
            for (int pg = 0; pg < 8; ++pg)
                pbv[pg] = *reinterpret_cast<const s16x8*>(smem + sa[pg] + roff);
            #pragma unroll
            for (int fl = 0; fl < 3; ++fl)
                #pragma unroll
                for (int pg = 0; pg < 8; ++pg)
                    acc[fl][pg] = __builtin_amdgcn_mfma_f32_16x16x32_bf16(
                        pa[r & 1][fl], pbv[pg], acc[fl][pg], 0, 0, 0);
        }

        // lane-local epilogue: closed-form cubic B-spline + silu residual
        #pragma unroll
        for (int pg = 0; pg < 8; ++pg) {
            const int wcol = pg * 16 + pix16;
            unsigned short sv = slab[(130 + wcol + 1) * SLAB_STRIDE + ic];
            float xv = __uint_as_float((unsigned)sv << 16);
            float u5 = (xv + 1.0f) * 2.5f;
            float cf = fminf(fmaxf(floorf(u5), 0.f), 4.f);
            int ccb = (int)cf;
            float t = u5 - cf;
            float omt = 1.f - t;
            float t2v = t * t, t3v = t2v * t;
            float bw0 = omt * omt * omt * (1.f / 6.f);
            float bw1 = (3.f * t3v - 6.f * t2v + 4.f) * (1.f / 6.f);
            float bw2 = (-3.f * t3v + 3.f * t2v + 3.f * t + 1.f) * (1.f / 6.f);
            float bw3 = t3v * (1.f / 6.f);
            float sl = xv / (1.f + __expf(-xv));
            float w[8];
            #pragma unroll
            for (int j = 0; j < 8; ++j) {
                float wv = 0.f;
                wv = (j == ccb)     ? bw0 : wv;
                wv = (j == ccb + 1) ? bw1 : wv;
                wv = (j == ccb + 2) ? bw2 : wv;
                wv = (j == ccb + 3) ? bw3 : wv;
                w[j] = wv;
            }
            float sp = 0.f;
            #pragma unroll
            for (int j = 0; j < 8; ++j)
                sp = fmaf(w[j], acc[j >> 2][pg][j & 3], sp);
            float uv = acc[2][pg][0];
            float rv = acc[2][pg][1];
            oreg[pg] += uv * sp + sl * rv;
        }
    }

    // write: o = q*8 + wm (o==31 is the zero-pad slot -> skip)
    const int o = q * 8 + wm;
    if (o < OUT_CH) {
        #pragma unroll
        for (int pg = 0; pg < 8; ++pg) {
            size_t oi = (size_t)o * NPIX + pb * 128 + pg * 16 + pix16;
            if (use_part)
                dst[(size_t)cg * OUT_CH * NPIX + oi] = oreg[pg];
            else
                atomicAdd(dst + oi, oreg[pg]);
        }
    }
}

__global__ void reduce_kernel(const float* __restrict__ part, float* __restrict__ out) {
    int e = blockIdx.x * 256 + threadIdx.x;
    if (e < OUT_CH * NPIX) {
        const size_t s = (size_t)OUT_CH * NPIX;
        float a = 0.f;
        #pragma unroll
        for (int k = 0; k < NCG; ++k) a += part[e + k * s];
        out[e] = a;
    }
}

extern "C" void kernel_launch(void* const* d_in, const int* in_sizes, int n_in,
                              void* d_out, int out_size, void* d_ws, size_t ws_size,
                              hipStream_t stream) {
    const float* x  = (const float*)d_in[0];   // (1,31,128,128)
    const float* gw = (const float*)d_in[1];   // (9610,31,3,3)
    const float* gb = (const float*)d_in[2];   // (9610,)
    float* outp = (float*)d_out;               // (1,31,128,128)
    unsigned short* bpack = (unsigned short*)d_ws;
    float* bias_pk = (float*)((char*)d_ws + BP3_B);
    float* part    = (float*)((char*)d_ws + BP3_B + (size_t)BIAS_ELE * 4);

    const long NU = (long)CHUNKS * NR * NFRG * 64;
    int pack_blocks = (int)((NU + BIAS_ELE + 255) / 256);
    pack_kernel<<<pack_blocks, 256, 0, stream>>>(gw, gb, bpack, bias_pk);

    if (ws_size >= WS_NEED) {
        main_kernel<<<1024, 512, LDS_BYTES, stream>>>(x, bpack, bias_pk, part, 1);
        reduce_kernel<<<(OUT_CH * NPIX + 255) / 256, 256, 0, stream>>>(part, outp);
    } else {
        hipMemsetAsync(d_out, 0, (size_t)out_size * sizeof(float), stream);
        main_kernel<<<1024, 512, LDS_BYTES, stream>>>(x, bpack, bias_pk, outp, 0);
    }
}

// Round 6
// 244.837 us; speedup vs baseline: 1.6803x; 1.6803x over previous
//
#include <hip/hip_runtime.h>
#include <hip/hip_bf16.h>

// ---- problem constants ----
#define OUT_CH   31
#define COEF_LEN 7688                 // 31*31*8
#define NPIX     16384                // 128*128
#define CHUNKS   31                   // KAN input channels (independent param groups)
#define NFRG     24                   // param fragments per chunk (384 padded M rows)
#define NR       9                    // K-steps: r = ky*3+kx; k-in-step = conv channel ci
#define FRAG_U16 512                  // u16 per fragment (64 lanes x 8)
#define BP3_B    ((size_t)CHUNKS*NR*NFRG*FRAG_U16*2)   // 6,856,704
#define BIAS_ELE (CHUNKS*NFRG*16)     // 11904 f32  (ws need = 6,904,320 B total)

using f32x4 = __attribute__((ext_vector_type(4))) float;
using s16x8 = __attribute__((ext_vector_type(8))) short;

__device__ __forceinline__ unsigned short f2bf(float f) {
    unsigned int u = __float_as_uint(f);
    unsigned int r = (u + 0x7FFFu + ((u >> 16) & 1u)) >> 16;
    return (unsigned short)r;
}

// ---------------------------------------------------------------------------
// Pack gen_w/gen_b into bf16 A-fragment layout + bias table.
//  bp3[i][r][f][lane][8] bf16.  M-row m = lane&15; k-in-step ci = (lane>>4)*8+jj.
//  param identity: o = (m>>2)*8 + f/3, jslot = (f%3)*4 + (m&3)
//    jslot 0..7 = coef j, 8 = univ, 9 = res, 10..11 = zero pad
//  One thread per (i, f, lane) computes all 9 r (36 B contiguous gw reads).
//  bias_pk[(i*24+f)*16 + m] f32 = gb[p].
// ---------------------------------------------------------------------------
__global__ void pack_kernel(const float* __restrict__ gw, const float* __restrict__ gb,
                            unsigned short* __restrict__ bp, float* __restrict__ bias_pk) {
    const int NMAIN = CHUNKS * NFRG * 64;          // 47616
    int tt = blockIdx.x * 256 + threadIdx.x;
    if (tt < NMAIN) {
        int lane = tt & 63;
        int u = tt >> 6;
        int f = u % NFRG;
        int i = u / NFRG;
        int m = lane & 15, q8 = lane >> 4;
        int o = (m >> 2) * 8 + f / 3;
        int jslot = (f % 3) * 4 + (m & 3);
        int p = -1;
        if (o < OUT_CH && jslot < 10) {
            if (jslot < 8)       p = i * 248 + o * 8 + jslot;
            else if (jslot == 8) p = COEF_LEN + i * 31 + o;
            else                 p = COEF_LEN + 961 + i * 31 + o;
        }
        s16x8 vr[NR];
        #pragma unroll
        for (int r = 0; r < NR; ++r)
            #pragma unroll
            for (int jj = 0; jj < 8; ++jj) vr[r][jj] = 0;
        #pragma unroll
        for (int jj = 0; jj < 8; ++jj) {
            int ci = q8 * 8 + jj;
            if (p >= 0 && ci < 31) {
                const float* gr = gw + (long)p * 279 + ci * 9;
                #pragma unroll
                for (int r = 0; r < NR; ++r) vr[r][jj] = (short)f2bf(gr[r]);
            }
        }
        #pragma unroll
        for (int r = 0; r < NR; ++r)
            *reinterpret_cast<s16x8*>(bp + (((size_t)i * NR + r) * NFRG + f) * FRAG_U16 + lane * 8) = vr[r];
    } else if (tt < NMAIN + BIAS_ELE) {
        int u = tt - NMAIN;
        int m = u & 15;
        int t2 = u >> 4;
        int f = t2 % NFRG;
        int i = t2 / NFRG;
        int o = (m >> 2) * 8 + f / 3;
        int jslot = (f % 3) * 4 + (m & 3);
        float val = 0.f;
        if (o < OUT_CH && jslot < 10) {
            int p;
            if (jslot < 8)       p = i * 248 + o * 8 + jslot;
            else if (jslot == 8) p = COEF_LEN + i * 31 + o;
            else                 p = COEF_LEN + 961 + i * 31 + o;
            val = gb[p];
        }
        bias_pk[u] = val;
    }
}

// ---------------------------------------------------------------------------
// Fused conv-GEMM + KAN epilogue; ONE chunk-slice per dispatch.
// Grid 512 = 128 rows x 4 col-tiles (32 px each); block 512 thr = 8 waves;
// wave wm owns frags [3wm,3wm+3) (zero A duplication across waves);
// lane owns pixel pg*16+pix16 and output o = q*8+wm (fully lane-local).
// All blocks in a dispatch read the SAME 1.73 MB param slice -> L2-resident
// on every XCD regardless of workgroup->XCD mapping. Barrier-free K-loop,
// reg-double-buffered A prefetch. Output chained across dispatches through
// d_out (first ? store : load+add+store) - no atomics, no ws partials.
// ---------------------------------------------------------------------------
__global__ void __launch_bounds__(512, 4)
main_kernel(const float* __restrict__ x, const unsigned short* __restrict__ bp3,
            const float* __restrict__ bias_pk, float* __restrict__ out,
            int c0, int nc, int first) {
    __shared__ unsigned short slab[3 * 34 * 40];   // 8160 B: [rr][cc][ch]
    const int tid = threadIdx.x;
    const int bid = blockIdx.x;
    const int row = bid >> 2;        // image row
    const int cb = bid & 3;          // 32-px column tile

    // slab: rows row-1..row+1, cols cb*32-1 .. cb*32+32, all 31 channels (bf16)
    for (int idx = tid; idx < 31 * 3 * 34; idx += 512) {
        int cc = idx % 34;
        int t = idx / 34;
        int rr = t % 3;
        int ci = t / 3;
        int hh = row - 1 + rr, ww = cb * 32 - 1 + cc;
        float v = 0.f;
        if ((unsigned)hh < 128u && (unsigned)ww < 128u)
            v = x[ci * NPIX + hh * 128 + ww];
        slab[(rr * 34 + cc) * 40 + ci] = f2bf(v);
    }
    __syncthreads();
    // ---- no further barriers ----

    const int lane = tid & 63;
    const int wm = tid >> 6;         // 0..7: frags [3*wm, 3*wm+3)
    const int q = lane >> 4;
    const int pix16 = lane & 15;
    const int lane8 = lane * 8;
    const char* slabb = (const char*)slab;

    int sa[2];
    #pragma unroll
    for (int pg = 0; pg < 2; ++pg)
        sa[pg] = (pg * 16 + pix16) * 80 + q * 16;   // byte offset, +roff later

    float oreg[2] = {0.f, 0.f};

    #pragma unroll 1
    for (int k = 0; k < nc; ++k) {
        const int ic = c0 + k;
        // acc init = bias (bias added exactly once, by the owning chunk)
        f32x4 acc[3][2];
        const float* bb = bias_pk + ((size_t)ic * NFRG + wm * 3) * 16 + q * 4;
        #pragma unroll
        for (int fl = 0; fl < 3; ++fl) {
            f32x4 b = *reinterpret_cast<const f32x4*>(bb + fl * 16);
            acc[fl][0] = b;
            acc[fl][1] = b;
        }

        const unsigned short* abase = bp3 + ((size_t)ic * NR * NFRG + wm * 3) * FRAG_U16 + lane8;
        s16x8 pa[2][3];
        #pragma unroll
        for (int fl = 0; fl < 3; ++fl)
            pa[0][fl] = *reinterpret_cast<const s16x8*>(abase + fl * FRAG_U16);

        #pragma unroll
        for (int r = 0; r < NR; ++r) {
            if (r + 1 < NR) {        // reg-dbuf prefetch of next K-step's A frags
                #pragma unroll
                for (int fl = 0; fl < 3; ++fl)
                    pa[(r + 1) & 1][fl] = *reinterpret_cast<const s16x8*>(
                        abase + ((r + 1) * NFRG + fl) * FRAG_U16);
            }
            const int roff = ((r / 3) * 34 + (r % 3)) * 80;
            s16x8 pbv[2];
            #pragma unroll
            for (int pg = 0; pg < 2; ++pg)
                pbv[pg] = *reinterpret_cast<const s16x8*>(slabb + sa[pg] + roff);
            #pragma unroll
            for (int fl = 0; fl < 3; ++fl)
                #pragma unroll
                for (int pg = 0; pg < 2; ++pg)
                    acc[fl][pg] = __builtin_amdgcn_mfma_f32_16x16x32_bf16(
                        pa[r & 1][fl], pbv[pg], acc[fl][pg], 0, 0, 0);
        }

        // lane-local epilogue: closed-form cubic B-spline + silu residual
        #pragma unroll
        for (int pg = 0; pg < 2; ++pg) {
            const int pl = pg * 16 + pix16;
            unsigned short sv = slab[(34 + pl + 1) * 40 + ic];   // center pixel, ch ic
            float xv = __uint_as_float((unsigned)sv << 16);
            float u5 = (xv + 1.0f) * 2.5f;
            float cf = fminf(fmaxf(floorf(u5), 0.f), 4.f);
            int ccb = (int)cf;
            float t = u5 - cf;
            float omt = 1.f - t;
            float t2v = t * t, t3v = t2v * t;
            float bw0 = omt * omt * omt * (1.f / 6.f);
            float bw1 = (3.f * t3v - 6.f * t2v + 4.f) * (1.f / 6.f);
            float bw2 = (-3.f * t3v + 3.f * t2v + 3.f * t + 1.f) * (1.f / 6.f);
            float bw3 = t3v * (1.f / 6.f);
            float sl = xv / (1.f + __expf(-xv));
            float w[8];
            #pragma unroll
            for (int j = 0; j < 8; ++j) {
                float wv = 0.f;
                wv = (j == ccb)     ? bw0 : wv;
                wv = (j == ccb + 1) ? bw1 : wv;
                wv = (j == ccb + 2) ? bw2 : wv;
                wv = (j == ccb + 3) ? bw3 : wv;
                w[j] = wv;
            }
            float sp = 0.f;
            #pragma unroll
            for (int j = 0; j < 8; ++j)
                sp = fmaf(w[j], acc[j >> 2][pg][j & 3], sp);
            oreg[pg] += acc[2][pg][0] * sp + sl * acc[2][pg][1];
        }
    }

    // chained output: disjoint (o, pixel) per lane -> race-free, deterministic
    const int o = q * 8 + wm;        // o==31 is the zero-pad slot
    if (o < OUT_CH) {
        #pragma unroll
        for (int pg = 0; pg < 2; ++pg) {
            size_t gi = (size_t)o * NPIX + row * 128 + cb * 32 + pg * 16 + pix16;
            if (first) out[gi] = oreg[pg];
            else       out[gi] += oreg[pg];
        }
    }
}

extern "C" void kernel_launch(void* const* d_in, const int* in_sizes, int n_in,
                              void* d_out, int out_size, void* d_ws, size_t ws_size,
                              hipStream_t stream) {
    const float* x  = (const float*)d_in[0];   // (1,31,128,128)
    const float* gw = (const float*)d_in[1];   // (9610,31,3,3)
    const float* gb = (const float*)d_in[2];   // (9610,)
    float* outp = (float*)d_out;               // (1,31,128,128)
    unsigned short* bpack = (unsigned short*)d_ws;          // 6,856,704 B
    float* bias_pk = (float*)((char*)d_ws + BP3_B);         // + 47,616 B

    const int NMAIN = CHUNKS * NFRG * 64;                   // 47616
    int pack_blocks = (NMAIN + BIAS_ELE + 255) / 256;       // 233
    pack_kernel<<<pack_blocks, 256, 0, stream>>>(gw, gb, bpack, bias_pk);

    // 4 dispatches, one chunk-slice each: slice (<=1.73 MB) is L2-resident on
    // every XCD regardless of workgroup->XCD mapping; output chains via d_out.
    int c0 = 0;
    for (int d = 0; d < 4; ++d) {
        int nc = (d < 3) ? 8 : 7;
        main_kernel<<<512, 512, 0, stream>>>(x, bpack, bias_pk, outp, c0, nc, d == 0 ? 1 : 0);
        c0 += nc;
    }
}